// Round 7
// baseline (183.058 us; speedup 1.0000x reference)
//
#include <hip/hip_runtime.h>

// Problem constants
#define N_PIX 4096   // 64*64 pixels
#define N_D   256    // feature dims
#define N_C   19     // classes
#define N_B   51     // bins
#define MAXM  4096   // stage capacity: any class size fits
#define N_BLOCKS_MAIN (18 * 256)

// ws layout (bytes)
#define OFF_LIST   0                      // int  [19][4096]
#define OFF_COUNTS 311296                 // int  [19]
#define OFF_ACC    311424                 // float[1]
#define OFF_TICKET 311428                 // int[1]

// --- K1: bucket pixel indices by class (blocks 0..18) + feature copy (19..255)
__global__ __launch_bounds__(256) void k_pre(const float* __restrict__ feature,
                                             const int* __restrict__ label,
                                             float* __restrict__ out,
                                             int* __restrict__ list,
                                             int* __restrict__ counts,
                                             float* __restrict__ acc,
                                             int* __restrict__ ticket) {
    const int b = blockIdx.x;
    if (b < N_C) {
        // ---- bucket class b: deterministic 4-wave compaction ----
        const int c = b;
        const int w = threadIdx.x >> 6;
        const int lane = threadIdx.x & 63;
        __shared__ int wcnt[4];
        if (c == 0 && threadIdx.x == 0) { *acc = 0.f; *ticket = 0; }  // ws poisoned

        const int q0 = w * 1024;   // phase 1: count matches in my quarter
        int cnt = 0;
        for (int base = 0; base < 1024; base += 64) {
            cnt += (int)__popcll(__ballot(label[q0 + base + lane] == c));
        }
        if (lane == 0) wcnt[w] = cnt;
        __syncthreads();
        int m = 0;
#pragma unroll
        for (int i = 0; i < 4; ++i) m += (i < w) ? wcnt[i] : 0;

        for (int base = 0; base < 1024; base += 64) {  // phase 2: scatter
            const int n = q0 + base + lane;
            const bool match = (label[n] == c);
            const unsigned long long mask = __ballot(match);
            if (match) list[c * N_PIX + m + __popcll(mask & ((1ull << lane) - 1ull))] = n;
            m += (int)__popcll(mask);
        }
        if (w == 3 && lane == 0) counts[c] = m;
    } else {
        // ---- feature pass-through: fully coalesced scalar copy (dst off by 4B)
        const int tid = (b - N_C) * 256 + threadIdx.x;
        const int nth = (256 - N_C) * 256;
        for (int i = tid; i < N_PIX * N_D; i += nth) out[1 + i] = feature[i];
    }
}

// --- K2: block = one (c,d); 4 waves split the pixel list into quarters.
// Pixels staged ONCE in LDS (scattered gather amortized over 4 waves x 51
// bins); hot loop = uniform ds_read_b128 broadcast + pure VALU/trans, zero
// cross-lane ops, 1 accumulator. lane = bin. Norm factors cancel -> dropped.
__global__ __launch_bounds__(256) void k_main(const float* __restrict__ feature,
                                              const int* __restrict__ list,
                                              const int* __restrict__ counts,
                                              float* __restrict__ acc,
                                              int* __restrict__ ticket,
                                              float* __restrict__ out) {
    const int c = blockIdx.x + 1;                 // class 0 never reaches the loss
    const int d = blockIdx.y;
    const int w = threadIdx.x >> 6;
    const int lane = threadIdx.x & 63;
    const int tid = threadIdx.x;
    const int m = counts[c];                      // block-uniform

    __shared__ float stage[MAXM];                 // 16 KB
    __shared__ float wred[8];
    __shared__ float pmerge[4][64];

    if (m > 0) {                                  // uniform branch (barriers safe)
        const float* __restrict__ row = feature + d * N_PIX;
        const int* __restrict__ lst = list + c * N_PIX;

        // -- stage (coalesced ds_write) + stats in one pass --
        float s1 = 0.f, s2 = 0.f;
        for (int j = tid; j < m; j += 256) {
            const float f = row[lst[j]];          // scattered, one round for m<=256
            stage[j] = f;
            s1 += f;
            s2 = fmaf(f, f, s2);
        }
#pragma unroll
        for (int off = 32; off; off >>= 1) {
            s1 += __shfl_xor(s1, off);
            s2 += __shfl_xor(s2, off);
        }
        if (lane == 0) { wred[2 * w] = s1; wred[2 * w + 1] = s2; }
        __syncthreads();                          // stats + stage visibility
        const float S1 = wred[0] + wred[2] + wred[4] + wred[6];
        const float S2 = wred[1] + wred[3] + wred[5] + wred[7];
        const float cnt = (float)m;
        const float mu = S1 / cnt;
        const float v = fmaxf(S2 / cnt - mu * mu, 1e-12f);
        const float LOG2E = 1.44269504088896340736f;
        const float as = -12.5f * LOG2E / v;      // sample: var/25 -> -0.5*25/v
        const float at = -0.5f * LOG2E / v;       // target
        // lanes >= 51: bin=1e18 -> as*t^2 -> -inf -> exp2 -> 0 (auto-masked)
        const float bin = (lane < N_B) ? fmaf(0.2f, (float)lane, -5.0f) : 1e18f;

        // -- KDE: my quarter [s,e), 8-aligned partitions for ds_read_b128 --
        const int q = ((m + 31) >> 5) << 3;       // ceil(m/4) rounded up to 8
        const int s = w * q;
        const int e = (s + q < m) ? s + q : m;
        float a0 = 0.f;
        int i = s;
        if (e > s) {
            const int nfull = s + ((e - s) & ~7);
            for (; i < nfull; i += 8) {           // uniform b128 broadcasts
                const float4 A = *(const float4*)&stage[i];
                const float4 B = *(const float4*)&stage[i + 4];
                float t;
                t = A.x - bin; a0 += __builtin_amdgcn_exp2f(as * t * t);
                t = A.y - bin; a0 += __builtin_amdgcn_exp2f(as * t * t);
                t = A.z - bin; a0 += __builtin_amdgcn_exp2f(as * t * t);
                t = A.w - bin; a0 += __builtin_amdgcn_exp2f(as * t * t);
                t = B.x - bin; a0 += __builtin_amdgcn_exp2f(as * t * t);
                t = B.y - bin; a0 += __builtin_amdgcn_exp2f(as * t * t);
                t = B.z - bin; a0 += __builtin_amdgcn_exp2f(as * t * t);
                t = B.w - bin; a0 += __builtin_amdgcn_exp2f(as * t * t);
            }
            for (; i < e; ++i) {                  // tail (<8)
                const float t = stage[i] - bin;
                a0 += __builtin_amdgcn_exp2f(as * t * t);
            }
        }
        pmerge[w][lane] = a0;                     // all waves write (0 if empty)
        __syncthreads();

        // -- wave 0: merge partitions, normalize, smooth-L1 --
        if (w == 0) {
            const float A = pmerge[0][lane] + pmerge[1][lane] +
                            pmerge[2][lane] + pmerge[3][lane];
            const float tt = bin - mu;
            const float targ = __builtin_amdgcn_exp2f(at * tt * tt);  // 0 for lane>=51
            float ss = A, st = targ;
#pragma unroll
            for (int off = 32; off; off >>= 1) {
                ss += __shfl_xor(ss, off);
                st += __shfl_xor(st, off);
            }
            const float hist = A / fmaxf(ss, 1e-30f);
            const float tgt  = targ / fmaxf(st, 1e-30f);
            const float diff = hist - tgt;
            const float ad = fabsf(diff);
            float sl1 = (ad < 1.f) ? 0.5f * diff * diff : ad - 0.5f;
#pragma unroll
            for (int off = 32; off; off >>= 1) sl1 += __shfl_down(sl1, off);
            if (lane == 0) atomicAdd(acc, sl1);
        }
    }
    // every block (incl. m==0) takes a ticket; acc-adds ordered via fence
    if (tid == 0) {
        __threadfence();
        const int t = atomicAdd(ticket, 1);       // device-scope
        if (t == N_BLOCKS_MAIN - 1) {             // last block finalizes
            int active = 0;
            for (int cc = 1; cc < N_C; ++cc) active += (counts[cc] > 0) ? 1 : 0;
            const float total = atomicAdd(acc, 0.0f);  // coherent read
            out[0] = total / (float)(N_D * N_B) / ((float)active + 1e-12f);
        }
    }
}

extern "C" void kernel_launch(void* const* d_in, const int* in_sizes, int n_in,
                              void* d_out, int out_size, void* d_ws, size_t ws_size,
                              hipStream_t stream) {
    const float* feature = (const float*)d_in[0];   // [1,256,64,64] fp32
    const int* label = (const int*)d_in[1];         // [1,1,64,64] int32
    float* out = (float*)d_out;                     // [0]=loss, [1..]=feature passthrough
    char* ws = (char*)d_ws;
    int* list = (int*)(ws + OFF_LIST);
    int* counts = (int*)(ws + OFF_COUNTS);
    float* acc = (float*)(ws + OFF_ACC);
    int* ticket = (int*)(ws + OFF_TICKET);

    k_pre<<<256, 256, 0, stream>>>(feature, label, out, list, counts, acc, ticket);
    dim3 grid(N_C - 1, N_D);
    k_main<<<grid, 256, 0, stream>>>(feature, list, counts, acc, ticket, out);
}